// Round 4
// baseline (6820.706 us; speedup 1.0000x reference)
//
#include <hip/hip_runtime.h>
#include <stdint.h>

#define B_SZ   2048
#define T_ENC  168
#define TEMPD  128
#define HID    1024
#define M_DEC  48

typedef _Float16 f16;
typedef _Float16 half8 __attribute__((ext_vector_type(8)));
typedef float    f32x4 __attribute__((ext_vector_type(4)));

__device__ __forceinline__ float sigf(float x)   { return 1.0f / (1.0f + __expf(-x)); }
__device__ __forceinline__ float tanhf_(float x) { return 2.0f / (1.0f + __expf(-2.0f * x)) - 1.0f; }

// Direct global->LDS, 16B per lane. LDS ptr must be wave-uniform base.
__device__ __forceinline__ void gld16(const void* g, void* l) {
    __builtin_amdgcn_global_load_lds(
        (const __attribute__((address_space(1))) void*)g,
        (__attribute__((address_space(3))) void*)l, 16, 0, 0);
}

#define WAITV6() asm volatile("s_waitcnt vmcnt(6)" ::: "memory")
#define WAITV0() asm volatile("s_waitcnt vmcnt(0)" ::: "memory")
#define SBAR()   do { __builtin_amdgcn_sched_barrier(0); \
                      __builtin_amdgcn_s_barrier();      \
                      __builtin_amdgcn_sched_barrier(0); } while (0)

// ---------------------------------------------------------------------------
// prep_xseq: temp_seq [B][T][128] fp32 -> xseq [T][B][128] f16
// ---------------------------------------------------------------------------
__global__ void prep_xseq(const float* __restrict__ temp_seq, f16* __restrict__ xseq)
{
    size_t i4 = ((size_t)blockIdx.x * blockDim.x + threadIdx.x) * 4;
    size_t b  = i4 / (T_ENC * TEMPD);
    size_t r  = i4 - b * (T_ENC * TEMPD);
    size_t t  = r >> 7;          // TEMPD = 128
    size_t d  = r & 127;
    float4 v = *(const float4*)(temp_seq + i4);
    f16* o = xseq + ((t * B_SZ) + b) * TEMPD + d;
    o[0] = (f16)v.x; o[1] = (f16)v.y; o[2] = (f16)v.z; o[3] = (f16)v.w;
}

// ---------------------------------------------------------------------------
// prep_misc: merged f16 weights [4H][128+1024], fcW f16, biases, wlast
// ---------------------------------------------------------------------------
__global__ void prep_misc(
    const float* __restrict__ encWih, const float* __restrict__ encWhh,
    const float* __restrict__ decWih, const float* __restrict__ decWhh,
    const float* __restrict__ encbih, const float* __restrict__ encbhh,
    const float* __restrict__ decbih, const float* __restrict__ decbhh,
    const float* __restrict__ fcW,
    f16* __restrict__ Wenc, f16* __restrict__ Wdec0, f16* __restrict__ fcWh,
    float* __restrict__ enc_b, float* __restrict__ dec_b, float* __restrict__ wlast)
{
    const int NW = 4 * HID * (TEMPD + HID);
    for (int idx = blockIdx.x * blockDim.x + threadIdx.x; idx < NW;
         idx += gridDim.x * blockDim.x) {
        int j = idx / (TEMPD + HID);
        int k = idx - j * (TEMPD + HID);
        Wenc[idx]  = (f16)(k < TEMPD ? encWih[j * TEMPD + k]
                                     : encWhh[(size_t)j * HID + (k - TEMPD)]);
        Wdec0[idx] = (f16)(k < TEMPD ? decWih[j * (TEMPD + 1) + k]
                                     : decWhh[(size_t)j * HID + (k - TEMPD)]);
        if (idx < TEMPD * HID) fcWh[idx] = (f16)fcW[idx];
        if (idx < 4 * HID) {
            enc_b[idx] = encbih[idx] + encbhh[idx];
            dec_b[idx] = decbih[idx] + decbhh[idx];
            wlast[idx] = decWih[idx * (TEMPD + 1) + TEMPD];
        }
    }
}

// ---------------------------------------------------------------------------
// prep_fold: WdecF = decWhh + decWih_x @ fcW ; biasF = decb + decWih_x @ fcb
// grid 256, block 256; each block: 16 j-rows x 1024 k. fcW streamed once/blk.
// ---------------------------------------------------------------------------
__global__ __launch_bounds__(256)
void prep_fold(
    const float* __restrict__ decWih, const float* __restrict__ decWhh,
    const float* __restrict__ decbih, const float* __restrict__ decbhh,
    const float* __restrict__ fcW,    const float* __restrict__ fcb,
    f16* __restrict__ WdecF, float* __restrict__ biasF)
{
    __shared__ float wih[16][TEMPD];
    __shared__ float fcbL[TEMPD];
    const int tid = threadIdx.x;
    const int j0  = blockIdx.x * 16;
    for (int i = tid; i < 16 * TEMPD; i += 256) {
        int r = i >> 7, p = i & 127;
        wih[r][p] = decWih[(size_t)(j0 + r) * (TEMPD + 1) + p];
    }
    if (tid < TEMPD) fcbL[tid] = fcb[tid];
    __syncthreads();
    for (int kk = 0; kk < 4; ++kk) {
        int k = kk * 256 + tid;
        float acc[16];
        #pragma unroll
        for (int r = 0; r < 16; ++r) acc[r] = decWhh[(size_t)(j0 + r) * HID + k];
        for (int p = 0; p < TEMPD; ++p) {
            float w = fcW[(size_t)p * HID + k];
            #pragma unroll
            for (int r = 0; r < 16; ++r) acc[r] += wih[r][p] * w;
        }
        #pragma unroll
        for (int r = 0; r < 16; ++r) WdecF[(size_t)(j0 + r) * HID + k] = (f16)acc[r];
    }
    if (tid < 16) {
        float b = decbih[j0 + tid] + decbhh[j0 + tid];
        for (int p = 0; p < TEMPD; ++p) b += wih[tid][p] * fcbL[p];
        biasF[j0 + tid] = b;
    }
}

// ---------------------------------------------------------------------------
// Fused LSTM step. Tile 128 batch rows x (4 gates x 64 cols). Grid 256 (1/CU),
// 512 threads = 8 waves. 3-deep counted-vmcnt pipeline, raw barriers.
// FULLK: K=1152 (x f16 [2048][128] + h), else K=1024 (h only).
// ---------------------------------------------------------------------------
template <int FULLK, int DEC>
__global__ __launch_bounds__(512, 2)
void lstm_step(
    const f16* __restrict__ xsrc,
    const f16* __restrict__ h_in, f16* __restrict__ h_out, float* __restrict__ c,
    const f16* __restrict__ W,                 // merged [4096][WS]
    const float* __restrict__ bias,
    const float* __restrict__ wlast, const float* __restrict__ speeds, int m_step)
{
    constexpr int NKC = FULLK ? 18 : 16;
    constexpr int WS  = FULLK ? (HID + TEMPD) : HID;

    __shared__ half8 ldsA[3][1024];   // 128 rows x 8 k-slots, swizzled (16KB x3)
    __shared__ half8 ldsW[3][2048];   // 256 N-rows x 8 k-slots (32KB x3)

    const int tid  = threadIdx.x;
    const int id   = blockIdx.x;
    const int swzb = (id & 7) * 32 + (id >> 3);   // bijective XCD swizzle (256=8*32)
    const int bm   = swzb & 15;
    const int bn   = swzb >> 4;
    const int lane = tid & 63;
    const int wid  = tid >> 6;
    const int wr   = wid >> 2;                     // 0..1 : 64-row half
    const int wc   = wid & 3;                      // 0..3 : 16-col quarter

    f32x4 acc[4][4];
    #pragma unroll
    for (int g = 0; g < 4; ++g)
        #pragma unroll
        for (int mr = 0; mr < 4; ++mr)
            acc[g][mr] = (f32x4){0.f, 0.f, 0.f, 0.f};

    // stage = exactly 6 gld16 per thread (2 A + 4 W) for every kc
    auto stageA = [&](int b, int kc) {
        if (FULLK && kc < 2) {
            #pragma unroll
            for (int it = 0; it < 2; ++it) {
                int p = wid * 128 + it * 64 + lane;
                int row = p >> 3, s = p & 7;
                gld16(xsrc + (size_t)(bm * 128 + row) * TEMPD + kc * 64 + ((s ^ (row & 7)) << 3),
                      &ldsA[b][wid * 128 + it * 64]);
            }
        } else {
            const int k0 = kc * 64 - (FULLK ? TEMPD : 0);
            #pragma unroll
            for (int it = 0; it < 2; ++it) {
                int p = wid * 128 + it * 64 + lane;
                int row = p >> 3, s = p & 7;
                gld16(h_in + (size_t)(bm * 128 + row) * HID + k0 + ((s ^ (row & 7)) << 3),
                      &ldsA[b][wid * 128 + it * 64]);
            }
        }
    };
    auto stageW = [&](int b, int kc) {
        const int k0 = kc * 64;
        #pragma unroll
        for (int it = 0; it < 4; ++it) {
            int p = wid * 256 + it * 64 + lane;
            int r = p >> 3, s = p & 7;
            int g = r >> 6, j = r & 63;
            gld16(W + (size_t)(g * HID + bn * 64 + j) * WS + k0 + ((s ^ (r & 7)) << 3),
                  &ldsW[b][wid * 256 + it * 64]);
        }
    };

    stageA(0, 0); stageW(0, 0);
    stageA(1, 1); stageW(1, 1);

    int cur = 0;
    for (int kc = 0; kc < NKC; ++kc) {
        if (kc == NKC - 1) { WAITV0(); } else { WAITV6(); }
        SBAR();   // after this: all waves' stage(kc) is in LDS; tile kc-1 reads retired
        if (kc + 2 < NKC) {
            int nb = cur + 2; if (nb >= 3) nb -= 3;
            stageA(nb, kc + 2);
            stageW(nb, kc + 2);
        }
        #pragma unroll
        for (int s = 0; s < 2; ++s) {
            const int ks = s * 4 + (lane >> 4);
            half8 af[4];
            #pragma unroll
            for (int mr = 0; mr < 4; ++mr) {
                int row = wr * 64 + mr * 16 + (lane & 15);
                af[mr] = ldsA[cur][row * 8 + (ks ^ (row & 7))];
            }
            half8 bf[4];
            #pragma unroll
            for (int g = 0; g < 4; ++g) {
                int r = g * 64 + wc * 16 + (lane & 15);
                bf[g] = ldsW[cur][r * 8 + (ks ^ (r & 7))];
            }
            __builtin_amdgcn_s_setprio(1);
            #pragma unroll
            for (int g = 0; g < 4; ++g)
                #pragma unroll
                for (int mr = 0; mr < 4; ++mr)
                    acc[g][mr] = __builtin_amdgcn_mfma_f32_16x16x32_f16(af[mr], bf[g], acc[g][mr], 0, 0, 0);
            __builtin_amdgcn_s_setprio(0);
        }
        cur = (cur == 2) ? 0 : cur + 1;
    }

    // ---- epilogue: LSTM pointwise ----
    const int col_g = bn * 64 + wc * 16 + (lane & 15);
    const float bi  = bias[col_g];
    const float bf_ = bias[HID + col_g];
    const float bg  = bias[2 * HID + col_g];
    const float bo  = bias[3 * HID + col_g];
    float wli = 0.f, wlf = 0.f, wlg = 0.f, wlo = 0.f;
    if (DEC) {
        wli = wlast[col_g];
        wlf = wlast[HID + col_g];
        wlg = wlast[2 * HID + col_g];
        wlo = wlast[3 * HID + col_g];
    }
    #pragma unroll
    for (int mr = 0; mr < 4; ++mr) {
        #pragma unroll
        for (int q = 0; q < 4; ++q) {
            int row_g = bm * 128 + wr * 64 + mr * 16 + (lane >> 4) * 4 + q;
            float pi = acc[0][mr][q] + bi;
            float pf = acc[1][mr][q] + bf_;
            float pg = acc[2][mr][q] + bg;
            float po = acc[3][mr][q] + bo;
            if (DEC) {
                float sp = speeds[(size_t)row_g * M_DEC + m_step];
                pi += sp * wli; pf += sp * wlf; pg += sp * wlg; po += sp * wlo;
            }
            float ii = sigf(pi), ff = sigf(pf), gg = tanhf_(pg), oo = sigf(po);
            size_t idx = (size_t)row_g * HID + col_g;
            float cn = ff * c[idx] + ii * gg;
            c[idx] = cn;
            h_out[idx] = (f16)(oo * tanhf_(cn));
        }
    }
}

// ---------------------------------------------------------------------------
// Batched fc over 16 stored h slots: preds = h @ fcW^T + fcb -> d_out.
// ---------------------------------------------------------------------------
__global__ __launch_bounds__(256, 2)
void fc_batch(const f16* __restrict__ hist, const f16* __restrict__ fcWh,
              const float* __restrict__ fcb, float* __restrict__ out, int mbase)
{
    __shared__ half8 ldsA[32 * 8];
    __shared__ half8 ldsW[128 * 8];
    const int tid  = threadIdx.x;
    const int lane = tid & 63;
    const int wid  = tid >> 6;
    const int wr   = wid >> 1;
    const int wc   = wid & 1;
    const int bm   = blockIdx.x;          // 0..1023
    const int slot = bm >> 6;
    const int b0   = (bm & 63) * 32;
    const f16* hrow = hist + (size_t)slot * (B_SZ * HID) + (size_t)b0 * HID;
    const int  mm   = mbase + slot;

    f32x4 acc[4];
    #pragma unroll
    for (int nr = 0; nr < 4; ++nr) acc[nr] = (f32x4){0.f, 0.f, 0.f, 0.f};

    for (int kc = 0; kc < HID / 64; ++kc) {
        const int k0 = kc * 64;
        {
            int row = tid >> 3, s = tid & 7;
            gld16(hrow + (size_t)row * HID + k0 + ((s ^ (row & 7)) << 3), &ldsA[wid * 64]);
        }
        #pragma unroll
        for (int it = 0; it < 4; ++it) {
            int p = wid * 256 + it * 64 + lane;
            int row = p >> 3, s = p & 7;
            gld16(fcWh + (size_t)row * HID + k0 + ((s ^ (row & 7)) << 3), &ldsW[wid * 256 + it * 64]);
        }
        __syncthreads();
        #pragma unroll
        for (int s2 = 0; s2 < 2; ++s2) {
            int arow = wr * 16 + (lane & 15);
            int slotk = s2 * 4 + (lane >> 4);
            half8 a = ldsA[arow * 8 + (slotk ^ (arow & 7))];
            #pragma unroll
            for (int nr = 0; nr < 4; ++nr) {
                int brow = wc * 64 + nr * 16 + (lane & 15);
                half8 bfr = ldsW[brow * 8 + (slotk ^ (brow & 7))];
                acc[nr] = __builtin_amdgcn_mfma_f32_16x16x32_f16(a, bfr, acc[nr], 0, 0, 0);
            }
        }
        __syncthreads();
    }
    #pragma unroll
    for (int nr = 0; nr < 4; ++nr)
        #pragma unroll
        for (int q = 0; q < 4; ++q) {
            int rloc = wr * 16 + (lane >> 4) * 4 + q;
            int col  = wc * 64 + nr * 16 + (lane & 15);
            out[(size_t)(b0 + rloc) * (M_DEC * TEMPD) + (size_t)mm * TEMPD + col] = acc[nr][q] + fcb[col];
        }
}

// ---------------------------------------------------------------------------
extern "C" void kernel_launch(void* const* d_in, const int* in_sizes, int n_in,
                              void* d_out, int out_size, void* d_ws, size_t ws_size,
                              hipStream_t stream)
{
    (void)in_sizes; (void)n_in; (void)out_size; (void)ws_size;
    const float* temp_seq   = (const float*)d_in[0];
    const float* avg_speeds = (const float*)d_in[1];
    const float* enc_Wih    = (const float*)d_in[2];
    const float* enc_Whh    = (const float*)d_in[3];
    const float* enc_bih    = (const float*)d_in[4];
    const float* enc_bhh    = (const float*)d_in[5];
    const float* dec_Wih    = (const float*)d_in[6];
    const float* dec_Whh    = (const float*)d_in[7];
    const float* dec_bih    = (const float*)d_in[8];
    const float* dec_bhh    = (const float*)d_in[9];
    const float* fc_W       = (const float*)d_in[10];
    const float* fc_b       = (const float*)d_in[11];
    float* out = (float*)d_out;

    char* ws = (char*)d_ws;
    size_t off = 0;
    auto alloc = [&](size_t bytes) -> void* {
        void* p = ws + off;
        off += (bytes + 255) & ~(size_t)255;
        return p;
    };
    const size_t SLOT = (size_t)B_SZ * HID;
    f16*   Wenc   = (f16*)alloc((size_t)4 * HID * (TEMPD + HID) * 2);
    f16*   Wdec0  = (f16*)alloc((size_t)4 * HID * (TEMPD + HID) * 2);
    f16*   WdecF  = (f16*)alloc((size_t)4 * HID * HID * 2);
    f16*   fcWh   = (f16*)alloc((size_t)TEMPD * HID * 2);
    float* enc_b  = (float*)alloc((size_t)4 * HID * 4);
    float* dec_b  = (float*)alloc((size_t)4 * HID * 4);
    float* biasF  = (float*)alloc((size_t)4 * HID * 4);
    float* wlast  = (float*)alloc((size_t)4 * HID * 4);
    f16*   hA     = (f16*)alloc(SLOT * 2);
    f16*   hB     = (f16*)alloc(SLOT * 2);
    float* cbuf   = (float*)alloc(SLOT * 4);
    f16*   xseq   = (f16*)alloc((size_t)T_ENC * B_SZ * TEMPD * 2);   // 88 MB
    f16*   hist   = (f16*)alloc(16 * SLOT * 2);                      // 64 MB

    hipMemsetAsync(hA,   0, SLOT * 2, stream);
    hipMemsetAsync(cbuf, 0, SLOT * 4, stream);

    prep_xseq<<<(B_SZ * T_ENC * TEMPD / 4 + 255) / 256, 256, 0, stream>>>(temp_seq, xseq);
    prep_misc<<<8192, 256, 0, stream>>>(
        enc_Wih, enc_Whh, dec_Wih, dec_Whh,
        enc_bih, enc_bhh, dec_bih, dec_bhh, fc_W,
        Wenc, Wdec0, fcWh, enc_b, dec_b, wlast);
    prep_fold<<<256, 256, 0, stream>>>(
        dec_Wih, dec_Whh, dec_bih, dec_bhh, fc_W, fc_b, WdecF, biasF);

    f16* hbuf[2] = {hA, hB};
    for (int t = 0; t < T_ENC; ++t) {
        lstm_step<1, 0><<<256, 512, 0, stream>>>(
            xseq + (size_t)t * (B_SZ * TEMPD),
            hbuf[t & 1], hbuf[(t + 1) & 1], cbuf,
            Wenc, enc_b, nullptr, nullptr, 0);
    }
    // T_ENC even -> final enc h is in hA; dec0 x = xseq last slice
    for (int m = 0; m < M_DEC; ++m) {
        const f16* hin = (m == 0) ? hA : hist + ((size_t)((m - 1) & 15)) * SLOT;
        f16* hout = hist + ((size_t)(m & 15)) * SLOT;
        if (m == 0) {
            lstm_step<1, 1><<<256, 512, 0, stream>>>(
                xseq + (size_t)(T_ENC - 1) * (B_SZ * TEMPD),
                hin, hout, cbuf, Wdec0, dec_b, wlast, avg_speeds, 0);
        } else {
            lstm_step<0, 1><<<256, 512, 0, stream>>>(
                nullptr, hin, hout, cbuf, WdecF, biasF, wlast, avg_speeds, m);
        }
        if ((m & 15) == 15) {
            fc_batch<<<1024, 256, 0, stream>>>(hist, fcWh, fc_b, out, m - 15);
        }
    }
}

// Round 5
// 6272.898 us; speedup vs baseline: 1.0873x; 1.0873x over previous
//
#include <hip/hip_runtime.h>
#include <stdint.h>

#define B_SZ   2048
#define T_ENC  168
#define TEMPD  128
#define HID    1024
#define M_DEC  48

typedef _Float16 f16;
typedef _Float16 half8 __attribute__((ext_vector_type(8)));
typedef float    f32x4 __attribute__((ext_vector_type(4)));

__device__ __forceinline__ float sigf(float x)   { return 1.0f / (1.0f + __expf(-x)); }
__device__ __forceinline__ float tanhf_(float x) { return 2.0f / (1.0f + __expf(-2.0f * x)) - 1.0f; }

// Direct global->LDS, 16B per lane. LDS ptr must be wave-uniform base.
__device__ __forceinline__ void gld16(const void* g, void* l) {
    __builtin_amdgcn_global_load_lds(
        (const __attribute__((address_space(1))) void*)g,
        (__attribute__((address_space(3))) void*)l, 16, 0, 0);
}

#define WAITV6() asm volatile("s_waitcnt vmcnt(6)" ::: "memory")
#define WAITV0() asm volatile("s_waitcnt vmcnt(0)" ::: "memory")
#define SBAR()   do { __builtin_amdgcn_sched_barrier(0); \
                      __builtin_amdgcn_s_barrier();      \
                      __builtin_amdgcn_sched_barrier(0); } while (0)
#define LGKM0()  do { asm volatile("s_waitcnt lgkmcnt(0)" ::: "memory"); \
                      __builtin_amdgcn_sched_barrier(0); } while (0)
#define MEMFENCE() asm volatile("" ::: "memory")

// ---------------------------------------------------------------------------
// prep_xseq: temp_seq [B][T][128] fp32 -> xseq [T][B][128] f16
// ---------------------------------------------------------------------------
__global__ void prep_xseq(const float* __restrict__ temp_seq, f16* __restrict__ xseq)
{
    size_t i4 = ((size_t)blockIdx.x * blockDim.x + threadIdx.x) * 4;
    size_t b  = i4 / (T_ENC * TEMPD);
    size_t r  = i4 - b * (T_ENC * TEMPD);
    size_t t  = r >> 7;
    size_t d  = r & 127;
    float4 v = *(const float4*)(temp_seq + i4);
    f16* o = xseq + ((t * B_SZ) + b) * TEMPD + d;
    o[0] = (f16)v.x; o[1] = (f16)v.y; o[2] = (f16)v.z; o[3] = (f16)v.w;
}

// ---------------------------------------------------------------------------
// prep_misc: merged f16 weights [4H][128+1024], fcW f16, biases, wlast
// ---------------------------------------------------------------------------
__global__ void prep_misc(
    const float* __restrict__ encWih, const float* __restrict__ encWhh,
    const float* __restrict__ decWih, const float* __restrict__ decWhh,
    const float* __restrict__ encbih, const float* __restrict__ encbhh,
    const float* __restrict__ decbih, const float* __restrict__ decbhh,
    const float* __restrict__ fcW,
    f16* __restrict__ Wenc, f16* __restrict__ Wdec0, f16* __restrict__ fcWh,
    float* __restrict__ enc_b, float* __restrict__ dec_b, float* __restrict__ wlast)
{
    const int NW = 4 * HID * (TEMPD + HID);
    for (int idx = blockIdx.x * blockDim.x + threadIdx.x; idx < NW;
         idx += gridDim.x * blockDim.x) {
        int j = idx / (TEMPD + HID);
        int k = idx - j * (TEMPD + HID);
        Wenc[idx]  = (f16)(k < TEMPD ? encWih[j * TEMPD + k]
                                     : encWhh[(size_t)j * HID + (k - TEMPD)]);
        Wdec0[idx] = (f16)(k < TEMPD ? decWih[j * (TEMPD + 1) + k]
                                     : decWhh[(size_t)j * HID + (k - TEMPD)]);
        if (idx < TEMPD * HID) fcWh[idx] = (f16)fcW[idx];
        if (idx < 4 * HID) {
            enc_b[idx] = encbih[idx] + encbhh[idx];
            dec_b[idx] = decbih[idx] + decbhh[idx];
            wlast[idx] = decWih[idx * (TEMPD + 1) + TEMPD];
        }
    }
}

// ---------------------------------------------------------------------------
// prep_fold: WdecF = decWhh + decWih_x @ fcW ; biasF = decb + decWih_x @ fcb
// ---------------------------------------------------------------------------
__global__ __launch_bounds__(256)
void prep_fold(
    const float* __restrict__ decWih, const float* __restrict__ decWhh,
    const float* __restrict__ decbih, const float* __restrict__ decbhh,
    const float* __restrict__ fcW,    const float* __restrict__ fcb,
    f16* __restrict__ WdecF, float* __restrict__ biasF)
{
    __shared__ float wih[16][TEMPD];
    __shared__ float fcbL[TEMPD];
    const int tid = threadIdx.x;
    const int j0  = blockIdx.x * 16;
    for (int i = tid; i < 16 * TEMPD; i += 256) {
        int r = i >> 7, p = i & 127;
        wih[r][p] = decWih[(size_t)(j0 + r) * (TEMPD + 1) + p];
    }
    if (tid < TEMPD) fcbL[tid] = fcb[tid];
    __syncthreads();
    for (int kk = 0; kk < 4; ++kk) {
        int k = kk * 256 + tid;
        float acc[16];
        #pragma unroll
        for (int r = 0; r < 16; ++r) acc[r] = decWhh[(size_t)(j0 + r) * HID + k];
        for (int p = 0; p < TEMPD; ++p) {
            float w = fcW[(size_t)p * HID + k];
            #pragma unroll
            for (int r = 0; r < 16; ++r) acc[r] += wih[r][p] * w;
        }
        #pragma unroll
        for (int r = 0; r < 16; ++r) WdecF[(size_t)(j0 + r) * HID + k] = (f16)acc[r];
    }
    if (tid < 16) {
        float b = decbih[j0 + tid] + decbhh[j0 + tid];
        for (int p = 0; p < TEMPD; ++p) b += wih[tid][p] * fcbL[p];
        biasF[j0 + tid] = b;
    }
}

// ---------------------------------------------------------------------------
// Fused LSTM step. Tile 128 batch rows x (4 gates x 64 cols). Grid 256 (1/CU),
// 512 threads = 8 waves. Per-kc: 2 lockstep phases (8 ds_read + partial stage
// issue + barrier + lgkm0 + 16 MFMA + barrier), counted vmcnt once per kc.
// FULLK: K=1152 (x f16 [2048][128] + h), else K=1024 (h only).
// ---------------------------------------------------------------------------
template <int FULLK, int DEC>
__global__ __launch_bounds__(512, 2)
void lstm_step(
    const f16* __restrict__ xsrc,
    const f16* __restrict__ h_in, f16* __restrict__ h_out, float* __restrict__ c,
    const f16* __restrict__ W,                 // merged [4096][WS]
    const float* __restrict__ bias,
    const float* __restrict__ wlast, const float* __restrict__ speeds, int m_step)
{
    constexpr int NKC = FULLK ? 18 : 16;
    constexpr int WS  = FULLK ? (HID + TEMPD) : HID;

    __shared__ half8 ldsA[3][1024];   // 128 rows x 8 k-slots, swizzled (16KB x3)
    __shared__ half8 ldsW[3][2048];   // 256 N-rows x 8 k-slots (32KB x3)

    const int tid  = threadIdx.x;
    const int id   = blockIdx.x;
    const int swzb = (id & 7) * 32 + (id >> 3);   // bijective XCD swizzle (256=8*32)
    const int bm   = swzb & 15;
    const int bn   = swzb >> 4;
    const int lane = tid & 63;
    const int wid  = tid >> 6;
    const int wr   = wid >> 2;                     // 0..1 : 64-row half
    const int wc   = wid & 3;                      // 0..3 : 16-col quarter

    f32x4 acc[4][4];
    #pragma unroll
    for (int g = 0; g < 4; ++g)
        #pragma unroll
        for (int mr = 0; mr < 4; ++mr)
            acc[g][mr] = (f32x4){0.f, 0.f, 0.f, 0.f};

    auto stageA = [&](int b, int kc) {
        if (FULLK && kc < 2) {
            #pragma unroll
            for (int it = 0; it < 2; ++it) {
                int p = wid * 128 + it * 64 + lane;
                int row = p >> 3, s = p & 7;
                gld16(xsrc + (size_t)(bm * 128 + row) * TEMPD + kc * 64 + ((s ^ (row & 7)) << 3),
                      &ldsA[b][wid * 128 + it * 64]);
            }
        } else {
            const int k0 = kc * 64 - (FULLK ? TEMPD : 0);
            #pragma unroll
            for (int it = 0; it < 2; ++it) {
                int p = wid * 128 + it * 64 + lane;
                int row = p >> 3, s = p & 7;
                gld16(h_in + (size_t)(bm * 128 + row) * HID + k0 + ((s ^ (row & 7)) << 3),
                      &ldsA[b][wid * 128 + it * 64]);
            }
        }
    };
    auto stageWhalf = [&](int b, int kc, int half) {
        const int k0 = kc * 64;
        #pragma unroll
        for (int it2 = 0; it2 < 2; ++it2) {
            int it = half * 2 + it2;
            int p = wid * 256 + it * 64 + lane;
            int r = p >> 3, s = p & 7;
            int g = r >> 6, j = r & 63;
            gld16(W + (size_t)(g * HID + bn * 64 + j) * WS + k0 + ((s ^ (r & 7)) << 3),
                  &ldsW[b][wid * 256 + it * 64]);
        }
    };

    half8 af[4], bf[4];
    auto rdfrags = [&](int cb, int s) {
        const int ks = s * 4 + (lane >> 4);
        #pragma unroll
        for (int mr = 0; mr < 4; ++mr) {
            int row = wr * 64 + mr * 16 + (lane & 15);
            af[mr] = ldsA[cb][row * 8 + (ks ^ (row & 7))];
        }
        #pragma unroll
        for (int g = 0; g < 4; ++g) {
            int r = g * 64 + wc * 16 + (lane & 15);
            bf[g] = ldsW[cb][r * 8 + (ks ^ (r & 7))];
        }
    };
    auto mfma16 = [&]() {
        __builtin_amdgcn_s_setprio(1);
        #pragma unroll
        for (int g = 0; g < 4; ++g)
            #pragma unroll
            for (int mr = 0; mr < 4; ++mr)
                acc[g][mr] = __builtin_amdgcn_mfma_f32_16x16x32_f16(af[mr], bf[g], acc[g][mr], 0, 0, 0);
        __builtin_amdgcn_s_setprio(0);
    };

    // ---- prologue: stage tiles 0,1; prefetch epilogue scalars into regs ----
    stageA(0, 0); stageWhalf(0, 0, 0); stageWhalf(0, 0, 1);
    MEMFENCE();   // pin: S(0) issued before everything below

    const int col_g = bn * 64 + wc * 16 + (lane & 15);
    const float bi  = bias[col_g];
    const float bf_ = bias[HID + col_g];
    const float bg  = bias[2 * HID + col_g];
    const float bo  = bias[3 * HID + col_g];
    float wli = 0.f, wlf = 0.f, wlg = 0.f, wlo = 0.f;
    float sp_r[4];
    if (DEC) {
        wli = wlast[col_g];
        wlf = wlast[HID + col_g];
        wlg = wlast[2 * HID + col_g];
        wlo = wlast[3 * HID + col_g];
        #pragma unroll
        for (int mr = 0; mr < 4; ++mr) {
            int row_g = bm * 128 + wr * 64 + mr * 16 + (lane >> 4) * 4;  // q varies 0..3
            sp_r[mr] = 0.f;
            (void)row_g;
        }
    }
    float creg[4][4];
    float spq[4][4];
    #pragma unroll
    for (int mr = 0; mr < 4; ++mr)
        #pragma unroll
        for (int q = 0; q < 4; ++q) {
            int row_g = bm * 128 + wr * 64 + mr * 16 + (lane >> 4) * 4 + q;
            creg[mr][q] = c[(size_t)row_g * HID + col_g];
            if (DEC) spq[mr][q] = speeds[(size_t)row_g * M_DEC + m_step];
        }

    stageA(1, 1); stageWhalf(1, 1, 0); stageWhalf(1, 1, 1);
    WAITV6();     // S(0) + scalars complete; S(1) may remain in flight
    SBAR();

    int cur = 0;
    for (int kc = 0; kc < NKC; ++kc) {
        int nb = cur + 2; if (nb >= 3) nb -= 3;
        // ---- phase 0 ----
        rdfrags(cur, 0);
        if (kc + 2 < NKC) { stageA(nb, kc + 2); stageWhalf(nb, kc + 2, 0); }
        SBAR();
        LGKM0();
        mfma16();
        SBAR();
        // ---- phase 1 ----
        rdfrags(cur, 1);
        if (kc + 2 < NKC) { stageWhalf(nb, kc + 2, 1); WAITV6(); }
        else              { WAITV0(); }
        SBAR();
        LGKM0();
        mfma16();
        SBAR();
        cur = (cur == 2) ? 0 : cur + 1;
    }

    // ---- epilogue: LSTM pointwise (all operands already in registers) ----
    #pragma unroll
    for (int mr = 0; mr < 4; ++mr) {
        #pragma unroll
        for (int q = 0; q < 4; ++q) {
            int row_g = bm * 128 + wr * 64 + mr * 16 + (lane >> 4) * 4 + q;
            float pi = acc[0][mr][q] + bi;
            float pf = acc[1][mr][q] + bf_;
            float pg = acc[2][mr][q] + bg;
            float po = acc[3][mr][q] + bo;
            if (DEC) {
                float sp = spq[mr][q];
                pi += sp * wli; pf += sp * wlf; pg += sp * wlg; po += sp * wlo;
            }
            float ii = sigf(pi), ff = sigf(pf), gg = tanhf_(pg), oo = sigf(po);
            size_t idx = (size_t)row_g * HID + col_g;
            float cn = ff * creg[mr][q] + ii * gg;
            c[idx] = cn;
            h_out[idx] = (f16)(oo * tanhf_(cn));
        }
    }
}

// ---------------------------------------------------------------------------
// Batched fc over 16 stored h slots: preds = h @ fcW^T + fcb -> d_out.
// ---------------------------------------------------------------------------
__global__ __launch_bounds__(256, 2)
void fc_batch(const f16* __restrict__ hist, const f16* __restrict__ fcWh,
              const float* __restrict__ fcb, float* __restrict__ out, int mbase)
{
    __shared__ half8 ldsA[32 * 8];
    __shared__ half8 ldsW[128 * 8];
    const int tid  = threadIdx.x;
    const int lane = tid & 63;
    const int wid  = tid >> 6;
    const int wr   = wid >> 1;
    const int wc   = wid & 1;
    const int bm   = blockIdx.x;
    const int slot = bm >> 6;
    const int b0   = (bm & 63) * 32;
    const f16* hrow = hist + (size_t)slot * (B_SZ * HID) + (size_t)b0 * HID;
    const int  mm   = mbase + slot;

    f32x4 acc[4];
    #pragma unroll
    for (int nr = 0; nr < 4; ++nr) acc[nr] = (f32x4){0.f, 0.f, 0.f, 0.f};

    for (int kc = 0; kc < HID / 64; ++kc) {
        const int k0 = kc * 64;
        {
            int row = tid >> 3, s = tid & 7;
            gld16(hrow + (size_t)row * HID + k0 + ((s ^ (row & 7)) << 3), &ldsA[wid * 64]);
        }
        #pragma unroll
        for (int it = 0; it < 4; ++it) {
            int p = wid * 256 + it * 64 + lane;
            int row = p >> 3, s = p & 7;
            gld16(fcWh + (size_t)row * HID + k0 + ((s ^ (row & 7)) << 3), &ldsW[wid * 256 + it * 64]);
        }
        __syncthreads();
        #pragma unroll
        for (int s2 = 0; s2 < 2; ++s2) {
            int arow = wr * 16 + (lane & 15);
            int slotk = s2 * 4 + (lane >> 4);
            half8 a = ldsA[arow * 8 + (slotk ^ (arow & 7))];
            #pragma unroll
            for (int nr = 0; nr < 4; ++nr) {
                int brow = wc * 64 + nr * 16 + (lane & 15);
                half8 bfr = ldsW[brow * 8 + (slotk ^ (brow & 7))];
                acc[nr] = __builtin_amdgcn_mfma_f32_16x16x32_f16(a, bfr, acc[nr], 0, 0, 0);
            }
        }
        __syncthreads();
    }
    #pragma unroll
    for (int nr = 0; nr < 4; ++nr)
        #pragma unroll
        for (int q = 0; q < 4; ++q) {
            int rloc = wr * 16 + (lane >> 4) * 4 + q;
            int col  = wc * 64 + nr * 16 + (lane & 15);
            out[(size_t)(b0 + rloc) * (M_DEC * TEMPD) + (size_t)mm * TEMPD + col] = acc[nr][q] + fcb[col];
        }
}

// ---------------------------------------------------------------------------
extern "C" void kernel_launch(void* const* d_in, const int* in_sizes, int n_in,
                              void* d_out, int out_size, void* d_ws, size_t ws_size,
                              hipStream_t stream)
{
    (void)in_sizes; (void)n_in; (void)out_size; (void)ws_size;
    const float* temp_seq   = (const float*)d_in[0];
    const float* avg_speeds = (const float*)d_in[1];
    const float* enc_Wih    = (const float*)d_in[2];
    const float* enc_Whh    = (const float*)d_in[3];
    const float* enc_bih    = (const float*)d_in[4];
    const float* enc_bhh    = (const float*)d_in[5];
    const float* dec_Wih    = (const float*)d_in[6];
    const float* dec_Whh    = (const float*)d_in[7];
    const float* dec_bih    = (const float*)d_in[8];
    const float* dec_bhh    = (const float*)d_in[9];
    const float* fc_W       = (const float*)d_in[10];
    const float* fc_b       = (const float*)d_in[11];
    float* out = (float*)d_out;

    char* ws = (char*)d_ws;
    size_t off = 0;
    auto alloc = [&](size_t bytes) -> void* {
        void* p = ws + off;
        off += (bytes + 255) & ~(size_t)255;
        return p;
    };
    const size_t SLOT = (size_t)B_SZ * HID;
    f16*   Wenc   = (f16*)alloc((size_t)4 * HID * (TEMPD + HID) * 2);
    f16*   Wdec0  = (f16*)alloc((size_t)4 * HID * (TEMPD + HID) * 2);
    f16*   WdecF  = (f16*)alloc((size_t)4 * HID * HID * 2);
    f16*   fcWh   = (f16*)alloc((size_t)TEMPD * HID * 2);
    float* enc_b  = (float*)alloc((size_t)4 * HID * 4);
    float* dec_b  = (float*)alloc((size_t)4 * HID * 4);
    float* biasF  = (float*)alloc((size_t)4 * HID * 4);
    float* wlast  = (float*)alloc((size_t)4 * HID * 4);
    f16*   hA     = (f16*)alloc(SLOT * 2);
    f16*   hB     = (f16*)alloc(SLOT * 2);
    float* cbuf   = (float*)alloc(SLOT * 4);
    f16*   xseq   = (f16*)alloc((size_t)T_ENC * B_SZ * TEMPD * 2);   // 88 MB
    f16*   hist   = (f16*)alloc(16 * SLOT * 2);                      // 64 MB

    hipMemsetAsync(hA,   0, SLOT * 2, stream);
    hipMemsetAsync(cbuf, 0, SLOT * 4, stream);

    prep_xseq<<<(B_SZ * T_ENC * TEMPD / 4 + 255) / 256, 256, 0, stream>>>(temp_seq, xseq);
    prep_misc<<<8192, 256, 0, stream>>>(
        enc_Wih, enc_Whh, dec_Wih, dec_Whh,
        enc_bih, enc_bhh, dec_bih, dec_bhh, fc_W,
        Wenc, Wdec0, fcWh, enc_b, dec_b, wlast);
    prep_fold<<<256, 256, 0, stream>>>(
        dec_Wih, dec_Whh, dec_bih, dec_bhh, fc_W, fc_b, WdecF, biasF);

    f16* hbuf[2] = {hA, hB};
    for (int t = 0; t < T_ENC; ++t) {
        lstm_step<1, 0><<<256, 512, 0, stream>>>(
            xseq + (size_t)t * (B_SZ * TEMPD),
            hbuf[t & 1], hbuf[(t + 1) & 1], cbuf,
            Wenc, enc_b, nullptr, nullptr, 0);
    }
    // T_ENC even -> final enc h is in hA; dec0 x = xseq last slice
    for (int m = 0; m < M_DEC; ++m) {
        const f16* hin = (m == 0) ? hA : hist + ((size_t)((m - 1) & 15)) * SLOT;
        f16* hout = hist + ((size_t)(m & 15)) * SLOT;
        if (m == 0) {
            lstm_step<1, 1><<<256, 512, 0, stream>>>(
                xseq + (size_t)(T_ENC - 1) * (B_SZ * TEMPD),
                hin, hout, cbuf, Wdec0, dec_b, wlast, avg_speeds, 0);
        } else {
            lstm_step<0, 1><<<256, 512, 0, stream>>>(
                nullptr, hin, hout, cbuf, WdecF, biasF, wlast, avg_speeds, m);
        }
        if ((m & 15) == 15) {
            fc_batch<<<1024, 256, 0, stream>>>(hist, fcWh, fc_b, out, m - 15);
        }
    }
}